// Round 11
// baseline (219.054 us; speedup 1.0000x reference)
//
#include <hip/hip_runtime.h>
#include <hip/hip_bf16.h>

#define T_TOKENS 8192
#define H_DIM    1024
#define N_EXP    8

#define BM 64
#define BN 128
#define BK 64

#define MAX_MSLOT 264
#define GEMM_GRID (MAX_MSLOT * 8)

typedef __attribute__((ext_vector_type(8))) __bf16 bf16x8;
typedef __attribute__((ext_vector_type(4))) float  f32x4;

#define AS1(p) ((const __attribute__((address_space(1))) void*)(p))
#define AS3(p) ((__attribute__((address_space(3))) void*)(p))

__device__ __forceinline__ unsigned short f2bf(float f) {
  unsigned u = __float_as_uint(f);
  u += 0x7fff + ((u >> 16) & 1);   // round-to-nearest-even
  return (unsigned short)(u >> 16);
}
__device__ __forceinline__ float bf2f(unsigned short s) {
  return __uint_as_float(((unsigned)s) << 16);
}

// ---------------- Router: one wave per token (fp32 math identical to validated R1-R10) ------
__global__ __launch_bounds__(256) void router_kernel(
    const float* __restrict__ x, const float* __restrict__ gw,
    const float* __restrict__ gb, float* __restrict__ logits_out,
    int* __restrict__ choice, float* __restrict__ wpair,
    unsigned short* __restrict__ xb)
{
  const int tid = threadIdx.x;
  const int lane = tid & 63;
  const int w = tid >> 6;
  const int t = blockIdx.x * 4 + w;
  const float* xr = x + (size_t)t * H_DIM;

  float acc[8];
  #pragma unroll
  for (int e = 0; e < 8; ++e) acc[e] = 0.f;

  #pragma unroll
  for (int i = 0; i < H_DIM / 64; ++i) {
    const int h = i * 64 + lane;
    const float xv = xr[h];
    if (xb) xb[(size_t)t * H_DIM + h] = f2bf(xv);
    const float4 g0 = *(const float4*)&gw[h * 8 + 0];
    const float4 g1 = *(const float4*)&gw[h * 8 + 4];
    acc[0] += xv * g0.x; acc[1] += xv * g0.y;
    acc[2] += xv * g0.z; acc[3] += xv * g0.w;
    acc[4] += xv * g1.x; acc[5] += xv * g1.y;
    acc[6] += xv * g1.z; acc[7] += xv * g1.w;
  }
  #pragma unroll
  for (int off = 32; off; off >>= 1) {
    #pragma unroll
    for (int e = 0; e < 8; ++e) acc[e] += __shfl_xor(acc[e], off);
  }
  if (lane == 0) {
    float lg[8];
    #pragma unroll
    for (int e = 0; e < 8; ++e) lg[e] = acc[e] + gb[e];
    #pragma unroll
    for (int e = 0; e < 8; ++e) logits_out[(size_t)t * N_EXP + e] = lg[e];
    int e0 = 0; float v0 = lg[0];
    #pragma unroll
    for (int e = 1; e < 8; ++e) { if (lg[e] > v0) { v0 = lg[e]; e0 = e; } }
    int e1 = -1; float v1 = -3.4e38f;
    #pragma unroll
    for (int e = 0; e < 8; ++e) { if (e != e0 && lg[e] > v1) { v1 = lg[e]; e1 = e; } }
    const float ew = expf(v1 - v0);
    const float r0 = 1.f / (1.f + ew);
    const float r1 = ew / (1.f + ew);
    wpair[2 * t + 0] = r0;
    wpair[2 * t + 1] = r1;
    choice[t] = e0 | (e1 << 4);
  }
}

// ---------------- Build per-expert pair lists (deterministic, token-ordered) ----------------
__global__ __launch_bounds__(256) void build_lists_kernel(
    const int* __restrict__ choice, int* __restrict__ cnt, int* __restrict__ lst)
{
  const int e = blockIdx.x;
  const int tid = threadIdx.x;
  __shared__ int sc[256];

  const int t0 = tid * 32;
  int ch[32];
  int cl = 0;
  #pragma unroll
  for (int j = 0; j < 32; ++j) {
    ch[j] = choice[t0 + j];
    if ((ch[j] & 15) == e) cl++;
    if ((ch[j] >> 4) == e) cl++;
  }
  sc[tid] = cl;
  __syncthreads();
  #pragma unroll
  for (int off = 1; off < 256; off <<= 1) {
    int u = (tid >= off) ? sc[tid - off] : 0;
    __syncthreads();
    sc[tid] += u;
    __syncthreads();
  }
  int pos = sc[tid] - cl;
  int* le = lst + e * T_TOKENS;
  #pragma unroll
  for (int j = 0; j < 32; ++j) {
    if ((ch[j] & 15) == e) le[pos++] = 2 * (t0 + j);
    if ((ch[j] >> 4) == e) le[pos++] = 2 * (t0 + j) + 1;
  }
  if (tid == 255) cnt[e] = sc[255];
}

// ---------------- Dense m-slot schedule (FALLBACK path only) --------------------------------
__global__ void sched_kernel(const int* __restrict__ cnt, int* __restrict__ msched)
{
  if (threadIdx.x == 0) {
    int s = 0;
    for (int e = 0; e < N_EXP; ++e) {
      const int nm = (cnt[e] + BM - 1) / BM;
      for (int i = 0; i < nm && s < MAX_MSLOT; ++i) msched[s++] = e | (i << 4);
    }
    for (; s < MAX_MSLOT; ++s) msched[s] = -1;
  }
}

// ---------------- W [e][k][n] fp32 -> Wt [e][n][k] bf16 (64x64 LDS-tiled transpose) ----------
__global__ __launch_bounds__(256) void wconv_kernel(
    const float* __restrict__ w, unsigned short* __restrict__ wt)
{
  __shared__ float t[64][65];
  const float* we = w + (size_t)blockIdx.z * H_DIM * H_DIM;
  unsigned short* wte = wt + (size_t)blockIdx.z * H_DIM * H_DIM;
  const int k0 = blockIdx.y * 64, n0 = blockIdx.x * 64;
  const int tid = threadIdx.x;
  #pragma unroll
  for (int r = 0; r < 4; ++r) {
    const int k = (tid >> 4) + r * 16;
    const int n = (tid & 15) * 4;
    const float4 v = *(const float4*)&we[(size_t)(k0 + k) * H_DIM + n0 + n];
    t[n + 0][k] = v.x; t[n + 1][k] = v.y; t[n + 2][k] = v.z; t[n + 3][k] = v.w;
  }
  __syncthreads();
  const int n = tid >> 2, kc = (tid & 3) * 16;
  unsigned short o[16];
  #pragma unroll
  for (int j = 0; j < 16; ++j) o[j] = f2bf(t[n][kc + j]);
  *(int4*)&wte[(size_t)(n0 + n) * H_DIM + k0 + kc] = *(int4*)&o[0];
  *(int4*)&wte[(size_t)(n0 + n) * H_DIM + k0 + kc + 8] = *(int4*)&o[8];
}

// ============================================================================================
// 256x256 8-wave double-buffered gather-GEMM (full path).
// Model: staging path ceiling ~24 B/cyc/CU; achievable TF ~ 14.5TB/s * BM*BN/(BM+BN).
// 256^2 intensity 128 FLOP/B -> ~1890 TF ceiling (vs 606 for 64x128 which R10 saturated).
// Grid = 256 blocks exactly (8m x 4n per expert; expert = blockIdx&7 -> one expert per XCD,
// its 2MB weight L2-resident). One __syncthreads per K-tile; next tile staged BEFORE compute
// so the 8 in-flight global_load_lds drain under ~2500cy of MFMA. cnt>2048 handled by the
// m-stride loop (rare; adds a second 2048-row pass for that block only).
// Regs: acc 8x4 f32x4 = 128 VGPR + frags/addr ~ 100 -> fits 256/wave (512thr = 2 waves/SIMD).
// ============================================================================================
template<int G1>
__global__ __launch_bounds__(512, 2) void gemm256_kernel(
    const unsigned short* __restrict__ A,      // G1: xb [T][H]; else h1 [pairs][H]
    const unsigned short* __restrict__ Wt,     // [e][n][k] bf16
    const float* __restrict__ b1,              // G1 only
    const int* __restrict__ cnt, const int* __restrict__ lst,
    const float* __restrict__ wpair,
    unsigned short* __restrict__ Out)          // G1: h1; else oe
{
  const int e   = blockIdx.x & 7;
  const int g   = blockIdx.x >> 3;
  const int mi  = g & 7;
  const int n0g = (g >> 3) * 256;
  const int c = cnt[e];
  const unsigned short* W = Wt + (size_t)e * H_DIM * H_DIM;
  const int* le = lst + e * T_TOKENS;

  __shared__ unsigned short As[2][256 * 64];   // 64 KB
  __shared__ unsigned short Bs[2][256 * 64];   // 64 KB

  const int tid  = threadIdx.x;
  const int lane = tid & 63;
  const int wid  = tid >> 6;        // 0..7
  const int wm   = wid >> 2;        // 0..1  (row half: 128 rows)
  const int wn   = wid & 3;         // 0..3  (col quarter: 64 cols)
  const int lrow8 = lane >> 3;
  const int csrc  = (lane & 7) ^ lrow8;   // pre-swizzled source chunk (matches read XOR)
  const int lr = lane & 15;
  const int kh = (lane >> 4) << 3;
  const int sw = (lane & 7) << 3;

  const unsigned short* bSrc[4];
  #pragma unroll
  for (int i = 0; i < 4; ++i)
    bSrc[i] = W + (size_t)(n0g + wid * 32 + i * 8 + lrow8) * H_DIM + csrc * 8;

  for (int m0 = mi * 256; m0 < c; m0 += 2048) {
    const unsigned short* aSrc[4];
    #pragma unroll
    for (int i = 0; i < 4; ++i) {
      const int gm = m0 + wid * 32 + i * 8 + lrow8;
      const int pair = (gm < c) ? le[gm] : le[0];
      const size_t row = G1 ? (size_t)(pair >> 1) : (size_t)pair;
      aSrc[i] = A + row * H_DIM + csrc * 8;
    }

    f32x4 acc[8][4];
    #pragma unroll
    for (int i = 0; i < 8; ++i)
      #pragma unroll
      for (int j = 0; j < 4; ++j) acc[i][j] = (f32x4){0.f, 0.f, 0.f, 0.f};

    // prologue: stage K-tile 0 into buffer 0
    #pragma unroll
    for (int i = 0; i < 4; ++i) {
      __builtin_amdgcn_global_load_lds(AS1(aSrc[i]), AS3(&As[0][(wid * 32 + i * 8) * 64]), 16, 0, 0);
      __builtin_amdgcn_global_load_lds(AS1(bSrc[i]), AS3(&Bs[0][(wid * 32 + i * 8) * 64]), 16, 0, 0);
    }

    for (int t = 0; t < 16; ++t) {
      __syncthreads();                       // tile t staged (drains in-flight loads)
      const int cb = t & 1;
      if (t < 15) {                          // issue tile t+1 BEFORE compute -> hides latency
        const int kt = (t + 1) * BK;
        #pragma unroll
        for (int i = 0; i < 4; ++i) {
          __builtin_amdgcn_global_load_lds(AS1(aSrc[i] + kt), AS3(&As[cb ^ 1][(wid * 32 + i * 8) * 64]), 16, 0, 0);
          __builtin_amdgcn_global_load_lds(AS1(bSrc[i] + kt), AS3(&Bs[cb ^ 1][(wid * 32 + i * 8) * 64]), 16, 0, 0);
        }
      }
      #pragma unroll
      for (int ks = 0; ks < 2; ++ks) {
        bf16x8 b[4];
        #pragma unroll
        for (int nf = 0; nf < 4; ++nf)
          b[nf] = *reinterpret_cast<const bf16x8*>(&Bs[cb][(wn * 64 + nf * 16 + lr) * 64 + ((ks * 32 + kh) ^ sw)]);
        #pragma unroll
        for (int mh = 0; mh < 2; ++mh) {
          bf16x8 a[4];
          #pragma unroll
          for (int mf = 0; mf < 4; ++mf)
            a[mf] = *reinterpret_cast<const bf16x8*>(&As[cb][(wm * 128 + mh * 64 + mf * 16 + lr) * 64 + ((ks * 32 + kh) ^ sw)]);
          #pragma unroll
          for (int mf = 0; mf < 4; ++mf)
            #pragma unroll
            for (int nf = 0; nf < 4; ++nf)
              acc[mh * 4 + mf][nf] = __builtin_amdgcn_mfma_f32_16x16x32_bf16(a[mf], b[nf], acc[mh * 4 + mf][nf], 0, 0, 0);
        }
      }
    }

    // epilogue
    #pragma unroll
    for (int mfp = 0; mfp < 8; ++mfp) {
      const int rbase = wm * 128 + mfp * 16 + ((lane >> 4) << 2);
      #pragma unroll
      for (int r = 0; r < 4; ++r) {
        const int gm = m0 + rbase + r;
        if (gm >= c) continue;
        const int pair = le[gm];
        unsigned short* dst = Out + (size_t)pair * H_DIM;
        if constexpr (G1) {
          const float gt = wpair[pair];      // fold router weight into h1 (g > 0)
          #pragma unroll
          for (int nf = 0; nf < 4; ++nf) {
            const int col = n0g + wn * 64 + nf * 16 + lr;
            const float v = acc[mfp][nf][r] + b1[e * H_DIM + col];
            dst[col] = f2bf(gt * fmaxf(v, 0.f));
          }
        } else {
          #pragma unroll
          for (int nf = 0; nf < 4; ++nf) {
            const int col = n0g + wn * 64 + nf * 16 + lr;
            dst[col] = f2bf(acc[mfp][nf][r]);
          }
        }
      }
    }
    // next m-iter prologue targets buf0, last read at t=14 and protected by sync(t=15): safe.
  }
}

// ---- FALLBACK small-tile kernels (64x128, validated R10) -----------------------------------
#define DECODE_SLOT()                                        \
  const int id = blockIdx.x;                                 \
  const int sv = msched[(id >> 6) * 8 + (id & 7)];           \
  if (sv < 0) return;                                        \
  const int e  = sv & 15;                                    \
  const int m0 = (sv >> 4) * BM;                             \
  const int n0 = ((id >> 3) & 7) * BN;

__global__ __launch_bounds__(256, 4) void gemm1f_kernel(
    const float* __restrict__ x,
    const unsigned short* __restrict__ w1t, const float* __restrict__ b1,
    const int* __restrict__ cnt, const int* __restrict__ lst,
    const int* __restrict__ msched,
    const float* __restrict__ wpair, unsigned short* __restrict__ h1)
{
  DECODE_SLOT();
  const int c = cnt[e];
  const unsigned short* W = w1t + (size_t)e * H_DIM * H_DIM;
  const int* le = lst + e * T_TOKENS;

  __shared__ unsigned short As[BM * BK];
  __shared__ unsigned short Bs[BN * BK];

  const int tid  = threadIdx.x;
  const int lane = tid & 63;
  const int wid  = tid >> 6;
  const int lrow8 = lane >> 3;
  const int csrc  = (lane & 7) ^ lrow8;

  const unsigned short* bSrc[4];
  #pragma unroll
  for (int i = 0; i < 4; ++i)
    bSrc[i] = W + (size_t)(n0 + wid * 32 + i * 8 + lrow8) * H_DIM + csrc * 8;

  const float* aSrcF[4]; int adst[4];
  #pragma unroll
  for (int i = 0; i < 4; ++i) {
    const int idx = i * 256 + tid;
    const int m = idx >> 4;
    const int k4 = (idx & 15) << 2;
    const int gm = m0 + m;
    const int pair = (gm < c) ? le[gm] : le[0];
    aSrcF[i] = x + (size_t)(pair >> 1) * H_DIM + k4;
    adst[i] = m * BK + (k4 ^ ((m & 7) << 3));
  }

  const int wr = (wid >> 1) * 32;
  const int wc = (wid & 1) * 64;
  const int lr = lane & 15;
  const int kh = (lane >> 4) << 3;
  const int sw = (lane & 7) << 3;

  f32x4 acc[2][4];
  #pragma unroll
  for (int i = 0; i < 2; ++i)
    #pragma unroll
    for (int j = 0; j < 4; ++j) acc[i][j] = (f32x4){0.f, 0.f, 0.f, 0.f};

  for (int kt = 0; kt < H_DIM; kt += BK) {
    __syncthreads();
    #pragma unroll
    for (int i = 0; i < 4; ++i)
      __builtin_amdgcn_global_load_lds(AS1(bSrc[i] + kt), AS3(&Bs[(wid * 32 + i * 8) * BK]), 16, 0, 0);
    #pragma unroll
    for (int i = 0; i < 4; ++i) {
      const float4 v = *(const float4*)(aSrcF[i] + kt);
      short4 s4;
      ((unsigned short*)&s4)[0] = f2bf(v.x);
      ((unsigned short*)&s4)[1] = f2bf(v.y);
      ((unsigned short*)&s4)[2] = f2bf(v.z);
      ((unsigned short*)&s4)[3] = f2bf(v.w);
      *(short4*)&As[adst[i]] = s4;
    }
    __syncthreads();
    #pragma unroll
    for (int kk = 0; kk < BK; kk += 32) {
      bf16x8 a[2], b[4];
      #pragma unroll
      for (int mi2 = 0; mi2 < 2; ++mi2)
        a[mi2] = *reinterpret_cast<const bf16x8*>(&As[(wr + mi2 * 16 + lr) * BK + ((kk + kh) ^ sw)]);
      #pragma unroll
      for (int ni = 0; ni < 4; ++ni)
        b[ni] = *reinterpret_cast<const bf16x8*>(&Bs[(wc + ni * 16 + lr) * BK + ((kk + kh) ^ sw)]);
      #pragma unroll
      for (int mi2 = 0; mi2 < 2; ++mi2)
        #pragma unroll
        for (int ni = 0; ni < 4; ++ni)
          acc[mi2][ni] = __builtin_amdgcn_mfma_f32_16x16x32_bf16(a[mi2], b[ni], acc[mi2][ni], 0, 0, 0);
    }
  }

  #pragma unroll
  for (int mi2 = 0; mi2 < 2; ++mi2) {
    const int rbase = wr + mi2 * 16 + ((lane >> 4) << 2);
    #pragma unroll
    for (int r = 0; r < 4; ++r) {
      const int gm = m0 + rbase + r;
      if (gm >= c) continue;
      const int pair = le[gm];
      const float g = wpair[pair];
      unsigned short* dst = h1 + (size_t)pair * H_DIM;
      #pragma unroll
      for (int ni = 0; ni < 4; ++ni) {
        const int col = n0 + wc + ni * 16 + lr;
        const float v = acc[mi2][ni][r] + b1[e * H_DIM + col];
        dst[col] = f2bf(g * fmaxf(v, 0.f));
      }
    }
  }
}

__global__ __launch_bounds__(256, 4) void gemm2_atomic_kernel(
    const unsigned short* __restrict__ h1, const unsigned short* __restrict__ w2t,
    const float* __restrict__ b2, const int* __restrict__ cnt,
    const int* __restrict__ lst, const int* __restrict__ msched,
    const float* __restrict__ wpair, float* __restrict__ out)
{
  DECODE_SLOT();
  const int c = cnt[e];
  const unsigned short* W = w2t + (size_t)e * H_DIM * H_DIM;
  const int* le = lst + e * T_TOKENS;

  __shared__ unsigned short As[BM * BK];
  __shared__ unsigned short Bs[BN * BK];

  const int tid  = threadIdx.x;
  const int lane = tid & 63;
  const int wid  = tid >> 6;
  const int lrow8 = lane >> 3;
  const int csrc  = (lane & 7) ^ lrow8;

  const unsigned short* aSrc[2];
  const unsigned short* bSrc[4];
  #pragma unroll
  for (int i = 0; i < 4; ++i)
    bSrc[i] = W + (size_t)(n0 + wid * 32 + i * 8 + lrow8) * H_DIM + csrc * 8;
  #pragma unroll
  for (int i = 0; i < 2; ++i) {
    const int m = wid * 16 + i * 8 + lrow8;
    const int gm = m0 + m;
    const int pair = (gm < c) ? le[gm] : le[0];
    aSrc[i] = h1 + (size_t)pair * H_DIM + csrc * 8;
  }

  const int wr = (wid >> 1) * 32;
  const int wc = (wid & 1) * 64;
  const int lr = lane & 15;
  const int kh = (lane >> 4) << 3;
  const int sw = (lane & 7) << 3;

  f32x4 acc[2][4];
  #pragma unroll
  for (int i = 0; i < 2; ++i)
    #pragma unroll
    for (int j = 0; j < 4; ++j) acc[i][j] = (f32x4){0.f, 0.f, 0.f, 0.f};

  for (int kt = 0; kt < H_DIM; kt += BK) {
    __syncthreads();
    #pragma unroll
    for (int i = 0; i < 4; ++i)
      __builtin_amdgcn_global_load_lds(AS1(bSrc[i] + kt), AS3(&Bs[(wid * 32 + i * 8) * BK]), 16, 0, 0);
    #pragma unroll
    for (int i = 0; i < 2; ++i)
      __builtin_amdgcn_global_load_lds(AS1(aSrc[i] + kt), AS3(&As[(wid * 16 + i * 8) * BK]), 16, 0, 0);
    __syncthreads();
    #pragma unroll
    for (int kk = 0; kk < BK; kk += 32) {
      bf16x8 a[2], b[4];
      #pragma unroll
      for (int mi2 = 0; mi2 < 2; ++mi2)
        a[mi2] = *reinterpret_cast<const bf16x8*>(&As[(wr + mi2 * 16 + lr) * BK + ((kk + kh) ^ sw)]);
      #pragma unroll
      for (int ni = 0; ni < 4; ++ni)
        b[ni] = *reinterpret_cast<const bf16x8*>(&Bs[(wc + ni * 16 + lr) * BK + ((kk + kh) ^ sw)]);
      #pragma unroll
      for (int mi2 = 0; mi2 < 2; ++mi2)
        #pragma unroll
        for (int ni = 0; ni < 4; ++ni)
          acc[mi2][ni] = __builtin_amdgcn_mfma_f32_16x16x32_bf16(a[mi2], b[ni], acc[mi2][ni], 0, 0, 0);
    }
  }

  #pragma unroll
  for (int mi2 = 0; mi2 < 2; ++mi2) {
    const int rbase = wr + mi2 * 16 + ((lane >> 4) << 2);
    #pragma unroll
    for (int r = 0; r < 4; ++r) {
      const int gm = m0 + rbase + r;
      if (gm >= c) continue;
      const int pair = le[gm];
      const int tok = pair >> 1;
      const float g = wpair[pair];
      float* dst = out + (size_t)tok * H_DIM;
      #pragma unroll
      for (int ni = 0; ni < 4; ++ni) {
        const int col = n0 + wc + ni * 16 + lr;
        atomicAdd(&dst[col], acc[mi2][ni][r] + g * b2[e * H_DIM + col]);
      }
    }
  }
}

// ---------------- Combine: out[t] = oe[2t] + oe[2t+1] + g0*b2[e0] + g1*b2[e1] ----------------
__global__ __launch_bounds__(256) void combine_kernel(
    const unsigned short* __restrict__ oe, const int* __restrict__ choice,
    const float* __restrict__ wpair, const float* __restrict__ b2,
    float* __restrict__ out)
{
  const int tid = threadIdx.x;
  const int t = blockIdx.x * 2 + (tid >> 7);
  const int col = (tid & 127) * 8;
  const int ch = choice[t];
  const int e0 = ch & 15, e1 = ch >> 4;
  const float g0 = wpair[2 * t], g1 = wpair[2 * t + 1];

  const unsigned short* o0 = oe + (size_t)(2 * t) * H_DIM + col;
  const unsigned short* o1 = oe + (size_t)(2 * t + 1) * H_DIM + col;
  int4 a = *(const int4*)o0;
  int4 b = *(const int4*)o1;
  const unsigned short* pa = (const unsigned short*)&a;
  const unsigned short* pb = (const unsigned short*)&b;
  const float* b2r0 = b2 + e0 * H_DIM + col;
  const float* b2r1 = b2 + e1 * H_DIM + col;
  float4 c0 = *(const float4*)&b2r0[0];
  float4 c1 = *(const float4*)&b2r0[4];
  float4 d0 = *(const float4*)&b2r1[0];
  float4 d1 = *(const float4*)&b2r1[4];
  float r[8];
  r[0] = bf2f(pa[0]) + bf2f(pb[0]) + g0 * c0.x + g1 * d0.x;
  r[1] = bf2f(pa[1]) + bf2f(pb[1]) + g0 * c0.y + g1 * d0.y;
  r[2] = bf2f(pa[2]) + bf2f(pb[2]) + g0 * c0.z + g1 * d0.z;
  r[3] = bf2f(pa[3]) + bf2f(pb[3]) + g0 * c0.w + g1 * d0.w;
  r[4] = bf2f(pa[4]) + bf2f(pb[4]) + g0 * c1.x + g1 * d1.x;
  r[5] = bf2f(pa[5]) + bf2f(pb[5]) + g0 * c1.y + g1 * d1.y;
  r[6] = bf2f(pa[6]) + bf2f(pb[6]) + g0 * c1.z + g1 * d1.z;
  r[7] = bf2f(pa[7]) + bf2f(pb[7]) + g0 * c1.w + g1 * d1.w;
  float* dst = out + (size_t)t * H_DIM + col;
  *(float4*)&dst[0] = *(float4*)&r[0];
  *(float4*)&dst[4] = *(float4*)&r[4];
}

extern "C" void kernel_launch(void* const* d_in, const int* in_sizes, int n_in,
                              void* d_out, int out_size, void* d_ws, size_t ws_size,
                              hipStream_t stream) {
  const float* x      = (const float*)d_in[0];
  const float* gate_w = (const float*)d_in[1];
  const float* gate_b = (const float*)d_in[2];
  const float* w1     = (const float*)d_in[3];
  const float* b1     = (const float*)d_in[4];
  const float* w2     = (const float*)d_in[5];
  const float* b2     = (const float*)d_in[6];

  float* out    = (float*)d_out;
  float* logits = out + (size_t)T_TOKENS * H_DIM;

  char* ws = (char*)d_ws;
  int*   cnt    = (int*)ws;                                        // 256 B
  int*   lst    = (int*)(ws + 256);                                // 256 KB
  float* wpr    = (float*)(ws + 262400);                           // 64 KB
  int*   choice = (int*)(ws + 327936);                             // 32 KB
  int*   msched = (int*)(ws + 360704);                             // 2 KB reserved
  char*  big    = ws + 362752;

  const size_t SZ_XB = (size_t)T_TOKENS * H_DIM * 2;          // 16 MB
  const size_t SZ_WT = (size_t)N_EXP * H_DIM * H_DIM * 2;     // 16 MB (reused w1t then w2t)
  const size_t SZ_H1 = (size_t)2 * T_TOKENS * H_DIM * 2;      // 32 MB
  const size_t SZ_OE = (size_t)2 * T_TOKENS * H_DIM * 2;      // 32 MB
  const bool full = ws_size >= (size_t)362752 + SZ_XB + SZ_WT + SZ_H1 + SZ_OE;

  unsigned short* xb = (unsigned short*)big;
  unsigned short* wt = (unsigned short*)(big + (full ? SZ_XB : 0));
  unsigned short* h1 = (unsigned short*)(big + (full ? SZ_XB : 0) + SZ_WT);
  unsigned short* oe = (unsigned short*)(big + SZ_XB + SZ_WT + SZ_H1);

  if (full) {
    router_kernel<<<T_TOKENS / 4, 256, 0, stream>>>(x, gate_w, gate_b, logits, choice, wpr, xb);
    build_lists_kernel<<<N_EXP, 256, 0, stream>>>(choice, cnt, lst);
    wconv_kernel<<<dim3(16, 16, 8), 256, 0, stream>>>(w1, wt);
    gemm256_kernel<1><<<256, 512, 0, stream>>>(xb, wt, b1, cnt, lst, wpr, h1);
    wconv_kernel<<<dim3(16, 16, 8), 256, 0, stream>>>(w2, wt);   // reuse wt (stream-serialized)
    gemm256_kernel<0><<<256, 512, 0, stream>>>(h1, wt, nullptr, cnt, lst, wpr, oe);
    combine_kernel<<<T_TOKENS / 2, 256, 0, stream>>>(oe, choice, wpr, b2, out);
  } else {
    hipMemsetAsync(out, 0, (size_t)T_TOKENS * H_DIM * sizeof(float), stream);
    router_kernel<<<T_TOKENS / 4, 256, 0, stream>>>(x, gate_w, gate_b, logits, choice, wpr, nullptr);
    build_lists_kernel<<<N_EXP, 256, 0, stream>>>(choice, cnt, lst);
    sched_kernel<<<1, 64, 0, stream>>>(cnt, msched);
    wconv_kernel<<<dim3(16, 16, 8), 256, 0, stream>>>(w1, wt);
    gemm1f_kernel<<<GEMM_GRID, 256, 0, stream>>>(x, wt, b1, cnt, lst, msched, wpr, h1);
    wconv_kernel<<<dim3(16, 16, 8), 256, 0, stream>>>(w2, wt);
    gemm2_atomic_kernel<<<GEMM_GRID, 256, 0, stream>>>(h1, wt, b2, cnt, lst, msched, wpr, out);
  }
}

// Round 12
// 165.999 us; speedup vs baseline: 1.3196x; 1.3196x over previous
//
#include <hip/hip_runtime.h>
#include <hip/hip_bf16.h>

#define T_TOKENS 8192
#define H_DIM    1024
#define N_EXP    8

#define BM 128
#define BN 128
#define BK 64

#define MAX_MSLOT 136
#define GEMM_GRID (17 * 64)   // 1088 block slots; msched sentinel for unused

typedef __attribute__((ext_vector_type(8))) __bf16 bf16x8;
typedef __attribute__((ext_vector_type(4))) float  f32x4;

#define AS1(p) ((const __attribute__((address_space(1))) void*)(p))
#define AS3(p) ((__attribute__((address_space(3))) void*)(p))

__device__ __forceinline__ unsigned short f2bf(float f) {
  unsigned u = __float_as_uint(f);
  u += 0x7fff + ((u >> 16) & 1);   // round-to-nearest-even
  return (unsigned short)(u >> 16);
}
__device__ __forceinline__ float bf2f(unsigned short s) {
  return __uint_as_float(((unsigned)s) << 16);
}

// ---------------- Router: one wave per token (fp32 math identical to validated R1-R10) ------
__global__ __launch_bounds__(256) void router_kernel(
    const float* __restrict__ x, const float* __restrict__ gw,
    const float* __restrict__ gb, float* __restrict__ logits_out,
    int* __restrict__ choice, float* __restrict__ wpair,
    unsigned short* __restrict__ xb)
{
  const int tid = threadIdx.x;
  const int lane = tid & 63;
  const int w = tid >> 6;
  const int t = blockIdx.x * 4 + w;
  const float* xr = x + (size_t)t * H_DIM;

  float acc[8];
  #pragma unroll
  for (int e = 0; e < 8; ++e) acc[e] = 0.f;

  #pragma unroll
  for (int i = 0; i < H_DIM / 64; ++i) {
    const int h = i * 64 + lane;
    const float xv = xr[h];
    if (xb) xb[(size_t)t * H_DIM + h] = f2bf(xv);
    const float4 g0 = *(const float4*)&gw[h * 8 + 0];
    const float4 g1 = *(const float4*)&gw[h * 8 + 4];
    acc[0] += xv * g0.x; acc[1] += xv * g0.y;
    acc[2] += xv * g0.z; acc[3] += xv * g0.w;
    acc[4] += xv * g1.x; acc[5] += xv * g1.y;
    acc[6] += xv * g1.z; acc[7] += xv * g1.w;
  }
  #pragma unroll
  for (int off = 32; off; off >>= 1) {
    #pragma unroll
    for (int e = 0; e < 8; ++e) acc[e] += __shfl_xor(acc[e], off);
  }
  if (lane == 0) {
    float lg[8];
    #pragma unroll
    for (int e = 0; e < 8; ++e) lg[e] = acc[e] + gb[e];
    #pragma unroll
    for (int e = 0; e < 8; ++e) logits_out[(size_t)t * N_EXP + e] = lg[e];
    int e0 = 0; float v0 = lg[0];
    #pragma unroll
    for (int e = 1; e < 8; ++e) { if (lg[e] > v0) { v0 = lg[e]; e0 = e; } }
    int e1 = -1; float v1 = -3.4e38f;
    #pragma unroll
    for (int e = 0; e < 8; ++e) { if (e != e0 && lg[e] > v1) { v1 = lg[e]; e1 = e; } }
    const float ew = expf(v1 - v0);
    const float r0 = 1.f / (1.f + ew);
    const float r1 = ew / (1.f + ew);
    wpair[2 * t + 0] = r0;
    wpair[2 * t + 1] = r1;
    choice[t] = e0 | (e1 << 4);
  }
}

// ---------------- Build per-expert pair lists (deterministic, token-ordered) ----------------
__global__ __launch_bounds__(256) void build_lists_kernel(
    const int* __restrict__ choice, int* __restrict__ cnt, int* __restrict__ lst)
{
  const int e = blockIdx.x;
  const int tid = threadIdx.x;
  __shared__ int sc[256];

  const int t0 = tid * 32;
  int ch[32];
  int cl = 0;
  #pragma unroll
  for (int j = 0; j < 32; ++j) {
    ch[j] = choice[t0 + j];
    if ((ch[j] & 15) == e) cl++;
    if ((ch[j] >> 4) == e) cl++;
  }
  sc[tid] = cl;
  __syncthreads();
  #pragma unroll
  for (int off = 1; off < 256; off <<= 1) {
    int u = (tid >= off) ? sc[tid - off] : 0;
    __syncthreads();
    sc[tid] += u;
    __syncthreads();
  }
  int pos = sc[tid] - cl;
  int* le = lst + e * T_TOKENS;
  #pragma unroll
  for (int j = 0; j < 32; ++j) {
    if ((ch[j] & 15) == e) le[pos++] = 2 * (t0 + j);
    if ((ch[j] >> 4) == e) le[pos++] = 2 * (t0 + j) + 1;
  }
  if (tid == 255) cnt[e] = sc[255];
}

// ---- Dense m-slot schedule + expert row-base prefix sums (base at msched[MAX_MSLOT+e]) -----
__global__ void sched_kernel(const int* __restrict__ cnt, int* __restrict__ msched)
{
  if (threadIdx.x == 0) {
    int s = 0;
    for (int e = 0; e < N_EXP; ++e) {
      const int nm = (cnt[e] + BM - 1) / BM;
      for (int i = 0; i < nm; ++i) msched[s++] = e | (i << 4);
    }
    for (; s < MAX_MSLOT; ++s) msched[s] = -1;
    int b = 0;
    for (int e = 0; e < N_EXP; ++e) { msched[MAX_MSLOT + e] = b; b += cnt[e]; }
  }
}

// ---------------- W [e][k][n] fp32 -> Wt [e][n][k] bf16 (64x64 LDS-tiled transpose) ----------
__global__ __launch_bounds__(256) void wconv_kernel(
    const float* __restrict__ w, unsigned short* __restrict__ wt)
{
  __shared__ float t[64][65];
  const float* we = w + (size_t)blockIdx.z * H_DIM * H_DIM;
  unsigned short* wte = wt + (size_t)blockIdx.z * H_DIM * H_DIM;
  const int k0 = blockIdx.y * 64, n0 = blockIdx.x * 64;
  const int tid = threadIdx.x;
  #pragma unroll
  for (int r = 0; r < 4; ++r) {
    const int k = (tid >> 4) + r * 16;
    const int n = (tid & 15) * 4;
    const float4 v = *(const float4*)&we[(size_t)(k0 + k) * H_DIM + n0 + n];
    t[n + 0][k] = v.x; t[n + 1][k] = v.y; t[n + 2][k] = v.z; t[n + 3][k] = v.w;
  }
  __syncthreads();
  const int n = tid >> 2, kc = (tid & 3) * 16;
  unsigned short o[16];
  #pragma unroll
  for (int j = 0; j < 16; ++j) o[j] = f2bf(t[n][kc + j]);
  *(int4*)&wte[(size_t)(n0 + n) * H_DIM + k0 + kc] = *(int4*)&o[0];
  *(int4*)&wte[(size_t)(n0 + n) * H_DIM + k0 + kc + 8] = *(int4*)&o[8];
}

// Dense-grid decode (R4/R8-proven XCD layout).
#define DECODE_SLOT()                                        \
  const int id = blockIdx.x;                                 \
  const int sv = msched[(id >> 6) * 8 + (id & 7)];           \
  if (sv < 0) return;                                        \
  const int e  = sv & 15;                                    \
  const int m0 = (sv >> 4) * BM;                             \
  const int n0 = ((id >> 3) & 7) * BN;

// ---------------- GEMM1: h1[base[e]+gm] = wpair * relu(x_gather @ W1[e] + b1[e]) ------------
// h1 is EXPERT-SORTED (row = base[e]+gm): epilogue writes are dense rows, and gemm2's
// A-staging becomes fully dense (no gather). (256,3) register ceiling per R5/R7.
template<int XB>
__global__ __launch_bounds__(256, 3) void gemm1_kernel(
    const float* __restrict__ x, const unsigned short* __restrict__ xb,
    const unsigned short* __restrict__ w1t, const float* __restrict__ b1,
    const int* __restrict__ cnt, const int* __restrict__ lst,
    const int* __restrict__ msched,
    const float* __restrict__ wpair, unsigned short* __restrict__ h1)
{
  DECODE_SLOT();
  const int c = cnt[e];
  const int rowbase = msched[MAX_MSLOT + e];
  const unsigned short* W = w1t + (size_t)e * H_DIM * H_DIM;  // [n][k] bf16
  const int* le = lst + e * T_TOKENS;

  __shared__ unsigned short As[BM * BK];
  __shared__ unsigned short Bs[BN * BK];

  const int tid  = threadIdx.x;
  const int lane = tid & 63;
  const int wid  = tid >> 6;

  const int lrow8 = lane >> 3;             // row within 8-row group
  const int csrc  = (lane & 7) ^ lrow8;    // pre-swizzled source chunk (matches read-side XOR)

  const unsigned short* bSrc[4];
  #pragma unroll
  for (int i = 0; i < 4; ++i) {
    const int r = wid * 32 + i * 8 + lrow8;
    bSrc[i] = W + (size_t)(n0 + r) * H_DIM + csrc * 8;
  }

  const unsigned short* aSrcB[4];
  const float* aSrcF[8]; int adst[8];
  if constexpr (XB) {
    #pragma unroll
    for (int i = 0; i < 4; ++i) {
      const int m = wid * 32 + i * 8 + lrow8;
      const int gm = m0 + m;
      const int pair = (gm < c) ? le[gm] : le[0];
      aSrcB[i] = xb + (size_t)(pair >> 1) * H_DIM + csrc * 8;
    }
  } else {
    #pragma unroll
    for (int i = 0; i < 8; ++i) {
      const int idx = i * 256 + tid;
      const int m = idx >> 4;
      const int k4 = (idx & 15) << 2;
      const int gm = m0 + m;
      const int pair = (gm < c) ? le[gm] : le[0];
      aSrcF[i] = x + (size_t)(pair >> 1) * H_DIM + k4;
      adst[i] = m * BK + (k4 ^ ((m & 7) << 3));
    }
  }

  const int wr = (wid >> 1) * 64;
  const int wc = (wid & 1) * 64;
  const int lr = lane & 15;
  const int kh = (lane >> 4) << 3;
  const int sw = (lane & 7) << 3;

  f32x4 acc[4][4];
  #pragma unroll
  for (int i = 0; i < 4; ++i)
    #pragma unroll
    for (int j = 0; j < 4; ++j) acc[i][j] = (f32x4){0.f, 0.f, 0.f, 0.f};

  for (int kt = 0; kt < H_DIM; kt += BK) {
    __syncthreads();
    #pragma unroll
    for (int i = 0; i < 4; ++i)
      __builtin_amdgcn_global_load_lds(AS1(bSrc[i] + kt), AS3(&Bs[(wid * 32 + i * 8) * BK]), 16, 0, 0);
    if constexpr (XB) {
      #pragma unroll
      for (int i = 0; i < 4; ++i)
        __builtin_amdgcn_global_load_lds(AS1(aSrcB[i] + kt), AS3(&As[(wid * 32 + i * 8) * BK]), 16, 0, 0);
    } else {
      #pragma unroll
      for (int i = 0; i < 8; ++i) {
        const float4 v = *(const float4*)(aSrcF[i] + kt);
        short4 s4;
        ((unsigned short*)&s4)[0] = f2bf(v.x);
        ((unsigned short*)&s4)[1] = f2bf(v.y);
        ((unsigned short*)&s4)[2] = f2bf(v.z);
        ((unsigned short*)&s4)[3] = f2bf(v.w);
        *(short4*)&As[adst[i]] = s4;
      }
    }
    __syncthreads();
    #pragma unroll
    for (int kk = 0; kk < BK; kk += 32) {
      bf16x8 a[4], b[4];
      #pragma unroll
      for (int mi = 0; mi < 4; ++mi) {
        const int row = wr + mi * 16 + lr;
        a[mi] = *reinterpret_cast<const bf16x8*>(&As[row * BK + ((kk + kh) ^ sw)]);
      }
      #pragma unroll
      for (int ni = 0; ni < 4; ++ni) {
        const int row = wc + ni * 16 + lr;
        b[ni] = *reinterpret_cast<const bf16x8*>(&Bs[row * BK + ((kk + kh) ^ sw)]);
      }
      #pragma unroll
      for (int mi = 0; mi < 4; ++mi)
        #pragma unroll
        for (int ni = 0; ni < 4; ++ni)
          acc[mi][ni] = __builtin_amdgcn_mfma_f32_16x16x32_bf16(a[mi], b[ni], acc[mi][ni], 0, 0, 0);
    }
  }

  #pragma unroll
  for (int mi = 0; mi < 4; ++mi) {
    const int rbase = wr + mi * 16 + ((lane >> 4) << 2);
    #pragma unroll
    for (int r = 0; r < 4; ++r) {
      const int gm = m0 + rbase + r;
      if (gm >= c) continue;
      const int pair = le[gm];
      const float g = wpair[pair];          // fold router weight into h1 (g > 0)
      unsigned short* dst = h1 + (size_t)(rowbase + gm) * H_DIM;   // DENSE sorted row
      #pragma unroll
      for (int ni = 0; ni < 4; ++ni) {
        const int col = n0 + wc + ni * 16 + lr;
        const float v = acc[mi][ni][r] + b1[e * H_DIM + col];
        dst[col] = f2bf(g * fmaxf(v, 0.f));
      }
    }
  }
}

// ---------------- GEMM2: oe[pair] = h1_sorted @ W2[e]  (DENSE A-staging) ---------------------
__global__ __launch_bounds__(256, 3) void gemm2_kernel(
    const unsigned short* __restrict__ h1, const unsigned short* __restrict__ w2t,
    const float* __restrict__ b2, const int* __restrict__ cnt,
    const int* __restrict__ lst, const int* __restrict__ msched,
    const float* __restrict__ wpair,
    unsigned short* __restrict__ oe, float* __restrict__ out)
{
  DECODE_SLOT();
  const int c = cnt[e];
  const int rowbase = msched[MAX_MSLOT + e];
  const unsigned short* W = w2t + (size_t)e * H_DIM * H_DIM;
  const int* le = lst + e * T_TOKENS;

  __shared__ unsigned short As[BM * BK];
  __shared__ unsigned short Bs[BN * BK];

  const int tid  = threadIdx.x;
  const int lane = tid & 63;
  const int wid  = tid >> 6;

  const int lrow8 = lane >> 3;
  const int csrc  = (lane & 7) ^ lrow8;

  const unsigned short* aSrc[4];
  const unsigned short* bSrc[4];
  #pragma unroll
  for (int i = 0; i < 4; ++i) {
    const int m = wid * 32 + i * 8 + lrow8;
    aSrc[i] = h1 + (size_t)(rowbase + m0 + m) * H_DIM + csrc * 8;   // DENSE rows, no gather
    bSrc[i] = W + (size_t)(n0 + m) * H_DIM + csrc * 8;
  }

  const int wr = (wid >> 1) * 64;
  const int wc = (wid & 1) * 64;
  const int lr = lane & 15;
  const int kh = (lane >> 4) << 3;
  const int sw = (lane & 7) << 3;

  f32x4 acc[4][4];
  #pragma unroll
  for (int i = 0; i < 4; ++i)
    #pragma unroll
    for (int j = 0; j < 4; ++j) acc[i][j] = (f32x4){0.f, 0.f, 0.f, 0.f};

  for (int kt = 0; kt < H_DIM; kt += BK) {
    __syncthreads();
    #pragma unroll
    for (int i = 0; i < 4; ++i) {
      __builtin_amdgcn_global_load_lds(AS1(bSrc[i] + kt), AS3(&Bs[(wid * 32 + i * 8) * BK]), 16, 0, 0);
      __builtin_amdgcn_global_load_lds(AS1(aSrc[i] + kt), AS3(&As[(wid * 32 + i * 8) * BK]), 16, 0, 0);
    }
    __syncthreads();
    #pragma unroll
    for (int kk = 0; kk < BK; kk += 32) {
      bf16x8 a[4], b[4];
      #pragma unroll
      for (int mi = 0; mi < 4; ++mi) {
        const int row = wr + mi * 16 + lr;
        a[mi] = *reinterpret_cast<const bf16x8*>(&As[row * BK + ((kk + kh) ^ sw)]);
      }
      #pragma unroll
      for (int ni = 0; ni < 4; ++ni) {
        const int row = wc + ni * 16 + lr;
        b[ni] = *reinterpret_cast<const bf16x8*>(&Bs[row * BK + ((kk + kh) ^ sw)]);
      }
      #pragma unroll
      for (int mi = 0; mi < 4; ++mi)
        #pragma unroll
        for (int ni = 0; ni < 4; ++ni)
          acc[mi][ni] = __builtin_amdgcn_mfma_f32_16x16x32_bf16(a[mi], b[ni], acc[mi][ni], 0, 0, 0);
    }
  }

  #pragma unroll
  for (int mi = 0; mi < 4; ++mi) {
    const int rbase = wr + mi * 16 + ((lane >> 4) << 2);
    #pragma unroll
    for (int r = 0; r < 4; ++r) {
      const int gm = m0 + rbase + r;
      if (gm >= c) continue;
      const int pair = le[gm];
      unsigned short* dst = oe + (size_t)pair * H_DIM;   // pair-indexed (combine unchanged)
      #pragma unroll
      for (int ni = 0; ni < 4; ++ni) {
        const int col = n0 + wc + ni * 16 + lr;
        dst[col] = f2bf(acc[mi][ni][r]);
      }
    }
  }
}

// ---- GEMM2 atomic fallback (no oe buffer): out[tok] += h1_sorted@W2 + g*b2 ----
__global__ __launch_bounds__(256, 3) void gemm2_atomic_kernel(
    const unsigned short* __restrict__ h1, const unsigned short* __restrict__ w2t,
    const float* __restrict__ b2, const int* __restrict__ cnt,
    const int* __restrict__ lst, const int* __restrict__ msched,
    const float* __restrict__ wpair, float* __restrict__ out)
{
  DECODE_SLOT();
  const int c = cnt[e];
  const int rowbase = msched[MAX_MSLOT + e];
  const unsigned short* W = w2t + (size_t)e * H_DIM * H_DIM;
  const int* le = lst + e * T_TOKENS;

  __shared__ unsigned short As[BM * BK];
  __shared__ unsigned short Bs[BN * BK];

  const int tid  = threadIdx.x;
  const int lane = tid & 63;
  const int wid  = tid >> 6;
  const int lrow8 = lane >> 3;
  const int csrc  = (lane & 7) ^ lrow8;

  const unsigned short* aSrc[4];
  const unsigned short* bSrc[4];
  #pragma unroll
  for (int i = 0; i < 4; ++i) {
    const int m = wid * 32 + i * 8 + lrow8;
    aSrc[i] = h1 + (size_t)(rowbase + m0 + m) * H_DIM + csrc * 8;
    bSrc[i] = W + (size_t)(n0 + m) * H_DIM + csrc * 8;
  }

  const int wr = (wid >> 1) * 64;
  const int wc = (wid & 1) * 64;
  const int lr = lane & 15;
  const int kh = (lane >> 4) << 3;
  const int sw = (lane & 7) << 3;

  f32x4 acc[4][4];
  #pragma unroll
  for (int i = 0; i < 4; ++i)
    #pragma unroll
    for (int j = 0; j < 4; ++j) acc[i][j] = (f32x4){0.f, 0.f, 0.f, 0.f};

  for (int kt = 0; kt < H_DIM; kt += BK) {
    __syncthreads();
    #pragma unroll
    for (int i = 0; i < 4; ++i) {
      __builtin_amdgcn_global_load_lds(AS1(bSrc[i] + kt), AS3(&Bs[(wid * 32 + i * 8) * BK]), 16, 0, 0);
      __builtin_amdgcn_global_load_lds(AS1(aSrc[i] + kt), AS3(&As[(wid * 32 + i * 8) * BK]), 16, 0, 0);
    }
    __syncthreads();
    #pragma unroll
    for (int kk = 0; kk < BK; kk += 32) {
      bf16x8 a[4], b[4];
      #pragma unroll
      for (int mi = 0; mi < 4; ++mi)
        a[mi] = *reinterpret_cast<const bf16x8*>(&As[(wr + mi * 16 + lr) * BK + ((kk + kh) ^ sw)]);
      #pragma unroll
      for (int ni = 0; ni < 4; ++ni)
        b[ni] = *reinterpret_cast<const bf16x8*>(&Bs[(wc + ni * 16 + lr) * BK + ((kk + kh) ^ sw)]);
      #pragma unroll
      for (int mi = 0; mi < 4; ++mi)
        #pragma unroll
        for (int ni = 0; ni < 4; ++ni)
          acc[mi][ni] = __builtin_amdgcn_mfma_f32_16x16x32_bf16(a[mi], b[ni], acc[mi][ni], 0, 0, 0);
    }
  }

  #pragma unroll
  for (int mi = 0; mi < 4; ++mi) {
    const int rbase = wr + mi * 16 + ((lane >> 4) << 2);
    #pragma unroll
    for (int r = 0; r < 4; ++r) {
      const int gm = m0 + rbase + r;
      if (gm >= c) continue;
      const int pair = le[gm];
      const int tok = pair >> 1;
      const float g = wpair[pair];
      float* dst = out + (size_t)tok * H_DIM;
      #pragma unroll
      for (int ni = 0; ni < 4; ++ni) {
        const int col = n0 + wc + ni * 16 + lr;
        atomicAdd(&dst[col], acc[mi][ni][r] + g * b2[e * H_DIM + col]);
      }
    }
  }
}

// ---------------- Combine: out[t] = oe[2t] + oe[2t+1] + g0*b2[e0] + g1*b2[e1] ----------------
__global__ __launch_bounds__(256) void combine_kernel(
    const unsigned short* __restrict__ oe, const int* __restrict__ choice,
    const float* __restrict__ wpair, const float* __restrict__ b2,
    float* __restrict__ out)
{
  const int tid = threadIdx.x;
  const int t = blockIdx.x * 2 + (tid >> 7);
  const int col = (tid & 127) * 8;
  const int ch = choice[t];
  const int e0 = ch & 15, e1 = ch >> 4;
  const float g0 = wpair[2 * t], g1 = wpair[2 * t + 1];

  const unsigned short* o0 = oe + (size_t)(2 * t) * H_DIM + col;
  const unsigned short* o1 = oe + (size_t)(2 * t + 1) * H_DIM + col;
  int4 a = *(const int4*)o0;
  int4 b = *(const int4*)o1;
  const unsigned short* pa = (const unsigned short*)&a;
  const unsigned short* pb = (const unsigned short*)&b;
  const float* b2r0 = b2 + e0 * H_DIM + col;
  const float* b2r1 = b2 + e1 * H_DIM + col;
  float4 c0 = *(const float4*)&b2r0[0];
  float4 c1 = *(const float4*)&b2r0[4];
  float4 d0 = *(const float4*)&b2r1[0];
  float4 d1 = *(const float4*)&b2r1[4];
  float r[8];
  r[0] = bf2f(pa[0]) + bf2f(pb[0]) + g0 * c0.x + g1 * d0.x;
  r[1] = bf2f(pa[1]) + bf2f(pb[1]) + g0 * c0.y + g1 * d0.y;
  r[2] = bf2f(pa[2]) + bf2f(pb[2]) + g0 * c0.z + g1 * d0.z;
  r[3] = bf2f(pa[3]) + bf2f(pb[3]) + g0 * c0.w + g1 * d0.w;
  r[4] = bf2f(pa[4]) + bf2f(pb[4]) + g0 * c1.x + g1 * d1.x;
  r[5] = bf2f(pa[5]) + bf2f(pb[5]) + g0 * c1.y + g1 * d1.y;
  r[6] = bf2f(pa[6]) + bf2f(pb[6]) + g0 * c1.z + g1 * d1.z;
  r[7] = bf2f(pa[7]) + bf2f(pb[7]) + g0 * c1.w + g1 * d1.w;
  float* dst = out + (size_t)t * H_DIM + col;
  *(float4*)&dst[0] = *(float4*)&r[0];
  *(float4*)&dst[4] = *(float4*)&r[4];
}

extern "C" void kernel_launch(void* const* d_in, const int* in_sizes, int n_in,
                              void* d_out, int out_size, void* d_ws, size_t ws_size,
                              hipStream_t stream) {
  const float* x      = (const float*)d_in[0];
  const float* gate_w = (const float*)d_in[1];
  const float* gate_b = (const float*)d_in[2];
  const float* w1     = (const float*)d_in[3];
  const float* b1     = (const float*)d_in[4];
  const float* w2     = (const float*)d_in[5];
  const float* b2     = (const float*)d_in[6];

  float* out    = (float*)d_out;
  float* logits = out + (size_t)T_TOKENS * H_DIM;

  char* ws = (char*)d_ws;
  int*   cnt    = (int*)ws;                                        // 256 B
  int*   lst    = (int*)(ws + 256);                                // 256 KB
  float* wpr    = (float*)(ws + 262400);                           // 64 KB
  int*   choice = (int*)(ws + 327936);                             // 32 KB
  int*   msched = (int*)(ws + 360704);                             // 136 slots + 8 base (1 KB)
  char*  big    = ws + 361728;

  const size_t SZ_XB = (size_t)T_TOKENS * H_DIM * 2;          // 16 MB
  const size_t SZ_WT = (size_t)N_EXP * H_DIM * H_DIM * 2;     // 16 MB (reused w1t then w2t)
  const size_t SZ_H1 = (size_t)2 * T_TOKENS * H_DIM * 2;      // 32 MB
  const size_t SZ_OE = (size_t)2 * T_TOKENS * H_DIM * 2;      // 32 MB
  const bool full = ws_size >= (size_t)361728 + SZ_XB + SZ_WT + SZ_H1 + SZ_OE;

  unsigned short* xb = (unsigned short*)big;
  unsigned short* wt = (unsigned short*)(big + (full ? SZ_XB : 0));
  unsigned short* h1 = (unsigned short*)(big + (full ? SZ_XB : 0) + SZ_WT);
  unsigned short* oe = (unsigned short*)(big + SZ_XB + SZ_WT + SZ_H1);

  if (full) {
    router_kernel<<<T_TOKENS / 4, 256, 0, stream>>>(x, gate_w, gate_b, logits, choice, wpr, xb);
    build_lists_kernel<<<N_EXP, 256, 0, stream>>>(choice, cnt, lst);
    sched_kernel<<<1, 64, 0, stream>>>(cnt, msched);
    wconv_kernel<<<dim3(16, 16, 8), 256, 0, stream>>>(w1, wt);
    gemm1_kernel<1><<<GEMM_GRID, 256, 0, stream>>>(x, xb, wt, b1, cnt, lst, msched, wpr, h1);
    wconv_kernel<<<dim3(16, 16, 8), 256, 0, stream>>>(w2, wt);   // reuse wt (stream-serialized)
    gemm2_kernel<<<GEMM_GRID, 256, 0, stream>>>(h1, wt, b2, cnt, lst, msched, wpr, oe, out);
    combine_kernel<<<T_TOKENS / 2, 256, 0, stream>>>(oe, choice, wpr, b2, out);
  } else {
    hipMemsetAsync(out, 0, (size_t)T_TOKENS * H_DIM * sizeof(float), stream);
    router_kernel<<<T_TOKENS / 4, 256, 0, stream>>>(x, gate_w, gate_b, logits, choice, wpr, nullptr);
    build_lists_kernel<<<N_EXP, 256, 0, stream>>>(choice, cnt, lst);
    sched_kernel<<<1, 64, 0, stream>>>(cnt, msched);
    wconv_kernel<<<dim3(16, 16, 8), 256, 0, stream>>>(w1, wt);
    gemm1_kernel<0><<<GEMM_GRID, 256, 0, stream>>>(x, xb, wt, b1, cnt, lst, msched, wpr, h1);
    wconv_kernel<<<dim3(16, 16, 8), 256, 0, stream>>>(w2, wt);
    gemm2_atomic_kernel<<<GEMM_GRID, 256, 0, stream>>>(h1, wt, b2, cnt, lst, msched, wpr, out);
  }
}